// Round 8
// baseline (85.342 us; speedup 1.0000x reference)
//
#include <hip/hip_runtime.h>

// ConvCapsLayer: A=32,B=32,K=3,P=4,STRIDE=2,ITERS=3 — fp32 in/out
// x: (2,32,32,512) f32   weights: (288,32,16) f32   out: (450,512) f32
//
// R21 = R20 (best, 82.34µs) with xt staging REMOVED: x read direct f32.
//   Rationale: stage's xt half (8.4MB rd + 4.2MB wr) only halves bytes of
//   x-loads that are coalesced AND L2-resident (hbm 4%) — pure overhead.
//   R17 tried this and spilled under the (64,4) bound (VGPR=64, scratch);
//   R20's (256,3) structure allocates cleanly (cap ~170). Single variable.
//   wt staging KEPT (the permutation is the real win: 32B/lane contiguous
//   vs 64 scattered 64B lines; reused 450x/j). Stage = 640 blocks, <1µs.
// Structure (R20): 4 independent waves per 256-thr block, no LDS/barriers;
//   unit=(blk&7)*1800+(blk>>3)*4+wv (bijective, XCD-chunked); 4 units of
//   a block share n -> x-tile L1-hot for waves 1-3.
// Per-wave body: lane owns i=lane+64k, k=0..4 (k=4 only lane<32); v[5][8]
//   v2f; unnormalized softmax (SE rides butterfly), split-first butterfly,
//   xor1/2 DPP, xor4/8/16 ds_swizzle, p via v_readlane.
// SPILL TRIPWIRE (recurring killer — R17/R18/R19): convcaps VGPR_Count
//   must be >=~100 and WRITE_SIZE ~1MB. VGPR 64/84 = allocator parked v
//   in scratch. Serial multi-unit waves are DEAD (R18/R19, 165+µs).
// Rejected: R12 4-wave+LDS x-stage (+3.4), R7 2-j ILP, R10 recompute-v,
//   R14 DPP/swizzle-alone (neutral), R18/R19 serial multi-unit (spill).
// KEPT: XCD chunking (R16, -1.4µs), 4-wave blocks (R20, -0.6µs).
// Budget: ~40.7µs harness d_ws-poison fill (268MB, unconditional,
//   untouchable) + ~0.5µs wt-stage + ~39µs main (latency plateau).

#define OH 15
#define OW 15
#define EPS_ 1e-8f

#define WT_ELEMS (32 * 5 * 64 * 16)         // 163,840 bf16 (320 KB)

typedef float v2f __attribute__((ext_vector_type(2)));

__device__ __forceinline__ v2f pfma(float a, v2f b, v2f c) {
    return __builtin_elementwise_fma((v2f){a, a}, b, c);
}
__device__ __forceinline__ float b_lo(unsigned int u) {
    union { unsigned int i; float f; } c; c.i = u << 16; return c.f;
}
__device__ __forceinline__ float b_hi(unsigned int u) {
    union { unsigned int i; float f; } c; c.i = u & 0xFFFF0000u; return c.f;
}
__device__ __forceinline__ unsigned short f2bf(float f) {
    union { float f; unsigned int i; } c; c.f = f;
    return (unsigned short)((c.i + 0x7FFFu + ((c.i >> 16) & 1u)) >> 16); // RNE
}

// ---- cross-lane helpers (all wave-local: lane = tid&63) ----
// DPP quad_perm[1,0,3,2] = xor1 ; quad_perm[2,3,0,1] = xor2
__device__ __forceinline__ float dppx1(float x) {
    return __builtin_bit_cast(float, __builtin_amdgcn_update_dpp(
        0, __builtin_bit_cast(int, x), 0xB1, 0xF, 0xF, true));
}
__device__ __forceinline__ float dppx2(float x) {
    return __builtin_bit_cast(float, __builtin_amdgcn_update_dpp(
        0, __builtin_bit_cast(int, x), 0x4E, 0xF, 0xF, true));
}
// ds_swizzle BitMode: offset = (xor<<10)|(or<<5)|and, and=0x1F
template <int OFF>
__device__ __forceinline__ float swzx(float x) {
    return __builtin_bit_cast(float, __builtin_amdgcn_ds_swizzle(
        __builtin_bit_cast(int, x), OFF));
}
__device__ __forceinline__ float rdlane(float x, int q) {
    return __builtin_bit_cast(float, __builtin_amdgcn_readlane(
        __builtin_bit_cast(int, x), q));
}

// wt-only staging: permute w -> wt_bf[j][k][lane][16]
__global__ __launch_bounds__(256) void stage_kernel(
    const float* __restrict__ w, unsigned short* __restrict__ wt)
{
    const int t2 = blockIdx.x * 256 + threadIdx.x;   // over WT_ELEMS
    const int j  = t2 / 5120;
    const int r  = t2 - j * 5120;
    const int k  = r >> 10;
    const int L  = (r >> 4) & 63;
    const int e  = r & 15;
    const int i  = L + 64 * k;
    wt[t2] = (i < 288) ? f2bf(w[(size_t)i * 512 + j * 16 + e])
                       : (unsigned short)0;
}

template <bool PERM>
__global__ __launch_bounds__(256, 3) void convcaps_kernel(
    const float* __restrict__ x,   // f32 direct (always)
    const void* __restrict__ wp_,  // PERM ? bf16 wt : f32 w
    float* __restrict__ out)       // (450,512)
{
    // 4 independent waves/block; wave wv handles unit
    //   (blk&7)*1800 + (blk>>3)*4 + wv   (bijective over 14400)
    // All 4 units of a block share n.
    const int blk  = blockIdx.x;              // 0..3599
    const int wv   = threadIdx.x >> 6;        // 0..3
    const int wid  = (blk & 7) * 1800 + (blk >> 3) * 4 + wv;
    const int n    = wid >> 5;                // patch 0..449
    const int j    = wid & 31;                // out capsule
    const int lane = threadIdx.x & 63;        // 0..63

    const int batch = n / (OH * OW);
    const int rem   = n - batch * OH * OW;
    const int oy    = rem / OW;
    const int ox    = rem - oy * OW;

    const bool has5 = (lane < 32);

    v2f v[5][8];                      // v[k][p*2+qq]
    // inactive 5th slot: logit = -inf so exp -> 0 (drops has5 selects later)
    float logit[5] = {0.f, 0.f, 0.f, 0.f, has5 ? 0.f : -1e30f};

    // ---- v[k] = X_i(4x4) * W_ij(4x4), i = lane + 64k ----
#pragma unroll
    for (int k = 0; k < 5; ++k) {
        if (k == 4 && !has5) {
#pragma unroll
            for (int m = 0; m < 8; ++m) v[4][m] = (v2f){0.f, 0.f};
        } else {
            const int i  = lane + 64 * k;
            const int a  = i & 31;
            const int kw = (i >> 5) % 3;
            const int kh = i / 96;
            const int h  = oy * 2 + kh;
            const int wc = ox * 2 + kw;
            const int pixel = (batch * 32 + h) * 32 + wc;

            // x[pixel][a][16] f32: 64B contiguous per lane, L2-resident
            const float4* xv = reinterpret_cast<const float4*>(
                x + ((size_t)pixel * 512 + a * 16));

            v2f wr2[4][2];
            if (PERM) {
                // wt[j][k][lane][16] bf16: 32B contiguous per lane
                const uint4* wb = reinterpret_cast<const uint4*>(
                    (const unsigned short*)wp_ + (((size_t)j * 5 + k) * 64 + lane) * 16);
                uint4 q0 = wb[0], q1 = wb[1];
                wr2[0][0] = (v2f){b_lo(q0.x), b_hi(q0.x)};
                wr2[0][1] = (v2f){b_lo(q0.y), b_hi(q0.y)};
                wr2[1][0] = (v2f){b_lo(q0.z), b_hi(q0.z)};
                wr2[1][1] = (v2f){b_lo(q0.w), b_hi(q0.w)};
                wr2[2][0] = (v2f){b_lo(q1.x), b_hi(q1.x)};
                wr2[2][1] = (v2f){b_lo(q1.y), b_hi(q1.y)};
                wr2[3][0] = (v2f){b_lo(q1.z), b_hi(q1.z)};
                wr2[3][1] = (v2f){b_lo(q1.w), b_hi(q1.w)};
            } else {
                const float4* wq = reinterpret_cast<const float4*>(
                    (const float*)wp_ + ((size_t)i * 32 + j) * 16);
                float4 w0 = wq[0], w1 = wq[1], w2 = wq[2], w3 = wq[3];
                wr2[0][0]=(v2f){w0.x,w0.y}; wr2[0][1]=(v2f){w0.z,w0.w};
                wr2[1][0]=(v2f){w1.x,w1.y}; wr2[1][1]=(v2f){w1.z,w1.w};
                wr2[2][0]=(v2f){w2.x,w2.y}; wr2[2][1]=(v2f){w2.z,w2.w};
                wr2[3][0]=(v2f){w3.x,w3.y}; wr2[3][1]=(v2f){w3.z,w3.w};
            }

            // row-at-a-time: only one float4 of x live per p
#pragma unroll
            for (int p = 0; p < 4; ++p) {
                float4 xr4 = xv[p];
#pragma unroll
                for (int qq = 0; qq < 2; ++qq) {
                    v2f acc = (v2f){0.f, 0.f};
                    acc = pfma(xr4.x, wr2[0][qq], acc);
                    acc = pfma(xr4.y, wr2[1][qq], acc);
                    acc = pfma(xr4.z, wr2[2][qq], acc);
                    acc = pfma(xr4.w, wr2[3][qq], acc);
                    v[k][p*2+qq] = acc;
                }
            }
        }
    }

#pragma unroll
    for (int it = 0; it < 3; ++it) {
        v2f c2[8];
        float se_loc;
        if (it == 0) {
#pragma unroll
            for (int m = 0; m < 8; ++m)
                c2[m] = v[0][m] + v[1][m] + v[2][m] + v[3][m] + v[4][m];
            se_loc = 0.f;  // normalizer is 288 (softmax of zeros)
        } else {
            const float e0 = __expf(logit[0]), e1 = __expf(logit[1]);
            const float e2 = __expf(logit[2]), e3 = __expf(logit[3]);
            const float e4 = __expf(logit[4]);   // 0 for lanes >= 32
#pragma unroll
            for (int m = 0; m < 8; ++m)
                c2[m] = pfma(e0, v[0][m],
                        pfma(e1, v[1][m],
                        pfma(e2, v[2][m],
                        pfma(e3, v[3][m],
                        pfma(e4, v[4][m], (v2f){0.f, 0.f})))));
            se_loc = e0 + e1 + e2 + e3 + e4;
        }

        float c[16];
#pragma unroll
        for (int m = 0; m < 8; ++m) { c[2*m] = c2[m].x; c[2*m+1] = c2[m].y; }

        // ---- split-first butterfly: comp bit b -> lane bit b ----
        float seR = se_loc;
        float s8[8];
        {
            const bool b = lane & 1;
#pragma unroll
            for (int m = 0; m < 8; ++m) {
                float send = b ? c[2*m]   : c[2*m+1];
                float keep = b ? c[2*m+1] : c[2*m];
                s8[m] = keep + dppx1(send);
            }
            if (it > 0) seR += dppx1(seR);
        }
        float s4[4];
        {
            const bool b = (lane >> 1) & 1;
#pragma unroll
            for (int m = 0; m < 4; ++m) {
                float send = b ? s8[2*m]   : s8[2*m+1];
                float keep = b ? s8[2*m+1] : s8[2*m];
                s4[m] = keep + dppx2(send);
            }
            if (it > 0) seR += dppx2(seR);
        }
        float s2v[2];
        {
            const bool b = (lane >> 2) & 1;
#pragma unroll
            for (int m = 0; m < 2; ++m) {
                float send = b ? s4[2*m]   : s4[2*m+1];
                float keep = b ? s4[2*m+1] : s4[2*m];
                s2v[m] = keep + swzx<0x101F>(send);
            }
            if (it > 0) seR += swzx<0x101F>(seR);
        }
        float s1;
        {
            const bool b = (lane >> 3) & 1;
            float send = b ? s2v[0] : s2v[1];
            float keep = b ? s2v[1] : s2v[0];
            s1 = keep + swzx<0x201F>(send);
            if (it > 0) seR += swzx<0x201F>(seR);
        }
        s1 += swzx<0x401F>(s1);    if (it > 0) seR += swzx<0x401F>(seR);
        s1 += __shfl_xor(s1, 32);  if (it > 0) seR += __shfl_xor(seR, 32);
        // s1 = sum_i (e_i or 1) * v_i[comp], comp = lane&15 ; seR = SE

        const float s = (it == 0) ? s1 * (1.0f / 288.0f)
                                  : s1 * __builtin_amdgcn_rcpf(seR);

        // ---- squash ----
        float t2 = s * s;
        t2 += dppx1(t2);
        t2 += dppx2(t2);
        t2 += swzx<0x101F>(t2);
        t2 += swzx<0x201F>(t2);
        const float n2 = t2;
        const float scale = n2 * __builtin_amdgcn_rcpf(1.0f + n2)
                               * __builtin_amdgcn_rsqf(n2 + EPS_);
        const float pval = s * scale;   // comp (lane&15) of p

        if (it < 2) {
            // p[q] identical at lanes q,q+16,q+32,q+48 -> readlane(q);
            // dot in packed v_pk_fma (acc.x even, acc.y odd chain).
            v2f pq2[8];
#pragma unroll
            for (int m = 0; m < 8; ++m)
                pq2[m] = (v2f){rdlane(pval, 2*m), rdlane(pval, 2*m+1)};
#pragma unroll
            for (int k = 0; k < 5; ++k) {
                v2f acc = (v2f){0.f, 0.f};
#pragma unroll
                for (int m = 0; m < 8; ++m)
                    acc = __builtin_elementwise_fma(v[k][m], pq2[m], acc);
                logit[k] += acc.x + acc.y;
            }
        } else {
            if (lane < 16)
                out[(size_t)n * 512 + j * 16 + lane] = pval;
        }
    }
}

extern "C" void kernel_launch(void* const* d_in, const int* in_sizes, int n_in,
                              void* d_out, int out_size, void* d_ws, size_t ws_size,
                              hipStream_t stream) {
    const float* x = (const float*)d_in[0];
    const float* w = (const float*)d_in[1];
    float* out = (float*)d_out;
    const int nblocks = 3600;   // 4 independent waves per block

    const size_t need = (size_t)WT_ELEMS * sizeof(unsigned short);
    if (d_ws != nullptr && ws_size >= need) {
        unsigned short* wt = (unsigned short*)d_ws;
        stage_kernel<<<WT_ELEMS / 256, 256, 0, stream>>>(w, wt);
        convcaps_kernel<true><<<nblocks, 256, 0, stream>>>(x, wt, out);
    } else {
        convcaps_kernel<false><<<nblocks, 256, 0, stream>>>(x, w, out);
    }
}

// Round 9
// 83.042 us; speedup vs baseline: 1.0277x; 1.0277x over previous
//
#include <hip/hip_runtime.h>

// ConvCapsLayer: A=32,B=32,K=3,P=4,STRIDE=2,ITERS=3 — fp32 in/out
// x: (2,32,32,512) f32   weights: (288,32,16) f32   out: (450,512) f32
//
// R22 = R20 (best, 82.34µs) verbatim, ONE change: __launch_bounds__(256,4)
//   on convcaps (cap 128 VGPR -> 4 waves/SIMD vs 3). Tests the LAST live
//   theory: residency. R17 counters: occ 33% (~3/SIMD), waves stalled ~85%
//   of cycles on serial VMEM+routing chains; more co-resident waves is the
//   textbook cover. Peak-live arithmetic: v(80)+wr2(8)+xpk(8)+misc(~20)
//   ~116 < 128, so a clean alloc is feasible. Prior (64,4) attempts were
//   confounded by spills on other edits; this is single-variable.
//   TRIPWIRE: VGPR_Count<100 or WRITE>>1MB or convcaps>45µs = spill ->
//   revert to R20. Clean+neutral = occupancy eliminated -> plateau.
// Structure (R20): 4 independent waves per 256-thr block, no LDS/barriers;
//   unit=(blk&7)*1800+(blk>>3)*4+wv (bijective, XCD-chunked); 4 units of
//   a block share n -> bf16 x-tile (~9KB) L1-hot for waves 1-3.
// Per-wave body: lane owns i=lane+64k, k=0..4 (k=4 only lane<32); v[5][8]
//   v2f; xt_bf[pixel][a][16] (4MB) + wt_bf[j][k][lane][16] (320KB) staged;
//   unnormalized softmax (SE rides butterfly), split-first butterfly,
//   xor1/2 DPP, xor4/8/16 ds_swizzle, p via v_readlane.
// SETTLED: xt staging KEEP (R21: f32-direct +3µs even clean — halved
//   bytes/insts + L1 footprint win). wt staging KEEP. XCD chunk KEEP
//   (R16 -1.4). 4-wave blocks KEEP (R20 -0.6). Serial multi-unit DEAD
//   (R18/R19 spill disasters). Issue/xlane surgery DEAD (R14/R15 neutral).
// Budget: ~40.5µs harness d_ws-poison fill (untouchable) + ~2.3µs stage
//   + ~39µs main (latency-bound: hbm 4%, VALU 41%, occ 33%).

#define OH 15
#define OW 15
#define EPS_ 1e-8f

#define XT_ELEMS (2 * 32 * 32 * 512)        // 2,097,152 bf16 (4 MB)
#define WT_ELEMS (32 * 5 * 64 * 16)         // 163,840 bf16 (320 KB)

typedef float v2f __attribute__((ext_vector_type(2)));

__device__ __forceinline__ v2f pfma(float a, v2f b, v2f c) {
    return __builtin_elementwise_fma((v2f){a, a}, b, c);
}
__device__ __forceinline__ float b_lo(unsigned int u) {
    union { unsigned int i; float f; } c; c.i = u << 16; return c.f;
}
__device__ __forceinline__ float b_hi(unsigned int u) {
    union { unsigned int i; float f; } c; c.i = u & 0xFFFF0000u; return c.f;
}
__device__ __forceinline__ unsigned short f2bf(float f) {
    union { float f; unsigned int i; } c; c.f = f;
    return (unsigned short)((c.i + 0x7FFFu + ((c.i >> 16) & 1u)) >> 16); // RNE
}

// ---- cross-lane helpers (all wave-local: lane = tid&63) ----
// DPP quad_perm[1,0,3,2] = xor1 ; quad_perm[2,3,0,1] = xor2
__device__ __forceinline__ float dppx1(float x) {
    return __builtin_bit_cast(float, __builtin_amdgcn_update_dpp(
        0, __builtin_bit_cast(int, x), 0xB1, 0xF, 0xF, true));
}
__device__ __forceinline__ float dppx2(float x) {
    return __builtin_bit_cast(float, __builtin_amdgcn_update_dpp(
        0, __builtin_bit_cast(int, x), 0x4E, 0xF, 0xF, true));
}
// ds_swizzle BitMode: offset = (xor<<10)|(or<<5)|and, and=0x1F
template <int OFF>
__device__ __forceinline__ float swzx(float x) {
    return __builtin_bit_cast(float, __builtin_amdgcn_ds_swizzle(
        __builtin_bit_cast(int, x), OFF));
}
__device__ __forceinline__ float rdlane(float x, int q) {
    return __builtin_bit_cast(float, __builtin_amdgcn_readlane(
        __builtin_bit_cast(int, x), q));
}

// merged staging: [0, XT_ELEMS) casts x; [XT_ELEMS, +WT_ELEMS) permutes w
__global__ __launch_bounds__(256) void stage_kernel(
    const float* __restrict__ x, const float* __restrict__ w,
    unsigned short* __restrict__ xt, unsigned short* __restrict__ wt)
{
    const int tid = blockIdx.x * 256 + threadIdx.x;
    if (tid < XT_ELEMS) {
        xt[tid] = f2bf(x[tid]);
    } else {
        const int t2 = tid - XT_ELEMS;      // over WT_ELEMS
        const int j  = t2 / 5120;
        const int r  = t2 - j * 5120;
        const int k  = r >> 10;
        const int L  = (r >> 4) & 63;
        const int e  = r & 15;
        const int i  = L + 64 * k;
        wt[t2] = (i < 288) ? f2bf(w[(size_t)i * 512 + j * 16 + e])
                           : (unsigned short)0;
    }
}

template <bool PERM>
__global__ __launch_bounds__(256, 4) void convcaps_kernel(
    const void* __restrict__ xp,   // PERM ? bf16 xt : f32 x
    const void* __restrict__ wp_,  // PERM ? bf16 wt : f32 w
    float* __restrict__ out)       // (450,512)
{
    // 4 independent waves/block; wave wv handles unit
    //   (blk&7)*1800 + (blk>>3)*4 + wv   (bijective over 14400)
    // All 4 units of a block share n (base%32 multiple of 4, <=28).
    const int blk  = blockIdx.x;              // 0..3599
    const int wv   = threadIdx.x >> 6;        // 0..3
    const int wid  = (blk & 7) * 1800 + (blk >> 3) * 4 + wv;
    const int n    = wid >> 5;                // patch 0..449
    const int j    = wid & 31;                // out capsule
    const int lane = threadIdx.x & 63;        // 0..63

    const int batch = n / (OH * OW);
    const int rem   = n - batch * OH * OW;
    const int oy    = rem / OW;
    const int ox    = rem - oy * OW;

    const bool has5 = (lane < 32);

    v2f v[5][8];                      // v[k][p*2+qq]
    // inactive 5th slot: logit = -inf so exp -> 0 (drops has5 selects later)
    float logit[5] = {0.f, 0.f, 0.f, 0.f, has5 ? 0.f : -1e30f};

    // ---- v[k] = X_i(4x4) * W_ij(4x4), i = lane + 64k ----
#pragma unroll
    for (int k = 0; k < 5; ++k) {
        if (k == 4 && !has5) {
#pragma unroll
            for (int m = 0; m < 8; ++m) v[4][m] = (v2f){0.f, 0.f};
        } else {
            const int i  = lane + 64 * k;
            const int a  = i & 31;
            const int kw = (i >> 5) % 3;
            const int kh = i / 96;
            const int h  = oy * 2 + kh;
            const int wc = ox * 2 + kw;
            const int pixel = (batch * 32 + h) * 32 + wc;

            v2f wr2[4][2];
            if (PERM) {
                // xt[pixel][a][16] bf16: 32B contiguous per lane
                const uint4* xb = reinterpret_cast<const uint4*>(
                    (const unsigned short*)xp + ((size_t)pixel * 512 + a * 16));
                uint4 u0 = xb[0], u1 = xb[1];
                // wt[j][k][lane][16] bf16: 32B contiguous per lane
                const uint4* wb = reinterpret_cast<const uint4*>(
                    (const unsigned short*)wp_ + (((size_t)j * 5 + k) * 64 + lane) * 16);
                uint4 q0 = wb[0], q1 = wb[1];
                wr2[0][0] = (v2f){b_lo(q0.x), b_hi(q0.x)};
                wr2[0][1] = (v2f){b_lo(q0.y), b_hi(q0.y)};
                wr2[1][0] = (v2f){b_lo(q0.z), b_hi(q0.z)};
                wr2[1][1] = (v2f){b_lo(q0.w), b_hi(q0.w)};
                wr2[2][0] = (v2f){b_lo(q1.x), b_hi(q1.x)};
                wr2[2][1] = (v2f){b_lo(q1.y), b_hi(q1.y)};
                wr2[3][0] = (v2f){b_lo(q1.z), b_hi(q1.z)};
                wr2[3][1] = (v2f){b_lo(q1.w), b_hi(q1.w)};
                // row-at-a-time unpack: only 4 x-floats live at once
                const unsigned int dwp[8] = {u0.x, u0.y, u0.z, u0.w,
                                             u1.x, u1.y, u1.z, u1.w};
#pragma unroll
                for (int p = 0; p < 4; ++p) {
                    const unsigned int da = dwp[2*p], db = dwp[2*p+1];
                    const float x0 = b_lo(da), x1 = b_hi(da);
                    const float x2 = b_lo(db), x3 = b_hi(db);
#pragma unroll
                    for (int qq = 0; qq < 2; ++qq) {
                        v2f acc = (v2f){0.f, 0.f};
                        acc = pfma(x0, wr2[0][qq], acc);
                        acc = pfma(x1, wr2[1][qq], acc);
                        acc = pfma(x2, wr2[2][qq], acc);
                        acc = pfma(x3, wr2[3][qq], acc);
                        v[k][p*2+qq] = acc;
                    }
                }
            } else {
                const float4* xv = reinterpret_cast<const float4*>(
                    (const float*)xp + ((size_t)pixel * 512 + a * 16));
                const float4* wq = reinterpret_cast<const float4*>(
                    (const float*)wp_ + ((size_t)i * 32 + j) * 16);
                float4 w0 = wq[0], w1 = wq[1], w2 = wq[2], w3 = wq[3];
                wr2[0][0]=(v2f){w0.x,w0.y}; wr2[0][1]=(v2f){w0.z,w0.w};
                wr2[1][0]=(v2f){w1.x,w1.y}; wr2[1][1]=(v2f){w1.z,w1.w};
                wr2[2][0]=(v2f){w2.x,w2.y}; wr2[2][1]=(v2f){w2.z,w2.w};
                wr2[3][0]=(v2f){w3.x,w3.y}; wr2[3][1]=(v2f){w3.z,w3.w};
#pragma unroll
                for (int p = 0; p < 4; ++p) {
                    float4 xr4 = xv[p];
#pragma unroll
                    for (int qq = 0; qq < 2; ++qq) {
                        v2f acc = (v2f){0.f, 0.f};
                        acc = pfma(xr4.x, wr2[0][qq], acc);
                        acc = pfma(xr4.y, wr2[1][qq], acc);
                        acc = pfma(xr4.z, wr2[2][qq], acc);
                        acc = pfma(xr4.w, wr2[3][qq], acc);
                        v[k][p*2+qq] = acc;
                    }
                }
            }
        }
    }

#pragma unroll
    for (int it = 0; it < 3; ++it) {
        v2f c2[8];
        float se_loc;
        if (it == 0) {
#pragma unroll
            for (int m = 0; m < 8; ++m)
                c2[m] = v[0][m] + v[1][m] + v[2][m] + v[3][m] + v[4][m];
            se_loc = 0.f;  // normalizer is 288 (softmax of zeros)
        } else {
            const float e0 = __expf(logit[0]), e1 = __expf(logit[1]);
            const float e2 = __expf(logit[2]), e3 = __expf(logit[3]);
            const float e4 = __expf(logit[4]);   // 0 for lanes >= 32
#pragma unroll
            for (int m = 0; m < 8; ++m)
                c2[m] = pfma(e0, v[0][m],
                        pfma(e1, v[1][m],
                        pfma(e2, v[2][m],
                        pfma(e3, v[3][m],
                        pfma(e4, v[4][m], (v2f){0.f, 0.f})))));
            se_loc = e0 + e1 + e2 + e3 + e4;
        }

        float c[16];
#pragma unroll
        for (int m = 0; m < 8; ++m) { c[2*m] = c2[m].x; c[2*m+1] = c2[m].y; }

        // ---- split-first butterfly: comp bit b -> lane bit b ----
        float seR = se_loc;
        float s8[8];
        {
            const bool b = lane & 1;
#pragma unroll
            for (int m = 0; m < 8; ++m) {
                float send = b ? c[2*m]   : c[2*m+1];
                float keep = b ? c[2*m+1] : c[2*m];
                s8[m] = keep + dppx1(send);
            }
            if (it > 0) seR += dppx1(seR);
        }
        float s4[4];
        {
            const bool b = (lane >> 1) & 1;
#pragma unroll
            for (int m = 0; m < 4; ++m) {
                float send = b ? s8[2*m]   : s8[2*m+1];
                float keep = b ? s8[2*m+1] : s8[2*m];
                s4[m] = keep + dppx2(send);
            }
            if (it > 0) seR += dppx2(seR);
        }
        float s2v[2];
        {
            const bool b = (lane >> 2) & 1;
#pragma unroll
            for (int m = 0; m < 2; ++m) {
                float send = b ? s4[2*m]   : s4[2*m+1];
                float keep = b ? s4[2*m+1] : s4[2*m];
                s2v[m] = keep + swzx<0x101F>(send);
            }
            if (it > 0) seR += swzx<0x101F>(seR);
        }
        float s1;
        {
            const bool b = (lane >> 3) & 1;
            float send = b ? s2v[0] : s2v[1];
            float keep = b ? s2v[1] : s2v[0];
            s1 = keep + swzx<0x201F>(send);
            if (it > 0) seR += swzx<0x201F>(seR);
        }
        s1 += swzx<0x401F>(s1);    if (it > 0) seR += swzx<0x401F>(seR);
        s1 += __shfl_xor(s1, 32);  if (it > 0) seR += __shfl_xor(seR, 32);
        // s1 = sum_i (e_i or 1) * v_i[comp], comp = lane&15 ; seR = SE

        const float s = (it == 0) ? s1 * (1.0f / 288.0f)
                                  : s1 * __builtin_amdgcn_rcpf(seR);

        // ---- squash ----
        float t2 = s * s;
        t2 += dppx1(t2);
        t2 += dppx2(t2);
        t2 += swzx<0x101F>(t2);
        t2 += swzx<0x201F>(t2);
        const float n2 = t2;
        const float scale = n2 * __builtin_amdgcn_rcpf(1.0f + n2)
                               * __builtin_amdgcn_rsqf(n2 + EPS_);
        const float pval = s * scale;   // comp (lane&15) of p

        if (it < 2) {
            // p[q] identical at lanes q,q+16,q+32,q+48 -> readlane(q);
            // dot in packed v_pk_fma (acc.x even, acc.y odd chain).
            v2f pq2[8];
#pragma unroll
            for (int m = 0; m < 8; ++m)
                pq2[m] = (v2f){rdlane(pval, 2*m), rdlane(pval, 2*m+1)};
#pragma unroll
            for (int k = 0; k < 5; ++k) {
                v2f acc = (v2f){0.f, 0.f};
#pragma unroll
                for (int m = 0; m < 8; ++m)
                    acc = __builtin_elementwise_fma(v[k][m], pq2[m], acc);
                logit[k] += acc.x + acc.y;
            }
        } else {
            if (lane < 16)
                out[(size_t)n * 512 + j * 16 + lane] = pval;
        }
    }
}

extern "C" void kernel_launch(void* const* d_in, const int* in_sizes, int n_in,
                              void* d_out, int out_size, void* d_ws, size_t ws_size,
                              hipStream_t stream) {
    const float* x = (const float*)d_in[0];
    const float* w = (const float*)d_in[1];
    float* out = (float*)d_out;
    const int nblocks = 3600;   // 4 independent waves per block

    const size_t need = (size_t)(XT_ELEMS + WT_ELEMS) * sizeof(unsigned short);
    if (d_ws != nullptr && ws_size >= need) {
        unsigned short* xt = (unsigned short*)d_ws;
        unsigned short* wt = xt + XT_ELEMS;
        stage_kernel<<<(XT_ELEMS + WT_ELEMS) / 256, 256, 0, stream>>>(x, w, xt, wt);
        convcaps_kernel<true><<<nblocks, 256, 0, stream>>>(xt, wt, out);
    } else {
        convcaps_kernel<false><<<nblocks, 256, 0, stream>>>(x, w, out);
    }
}

// Round 10
// 82.142 us; speedup vs baseline: 1.0390x; 1.0110x over previous
//
#include <hip/hip_runtime.h>

// ConvCapsLayer: A=32,B=32,K=3,P=4,STRIDE=2,ITERS=3 — fp32 in/out
// x: (2,32,32,512) f32   weights: (288,32,16) f32   out: (450,512) f32
//
// R23 = R20 VERBATIM (best measured: 82.34µs). Revert of R22's (256,4)
//   bound (clean alloc but neutral -> occupancy formally eliminated).
// Structure: 4 independent waves per 256-thr block, no LDS/barriers;
//   unit=(blk&7)*1800+(blk>>3)*4+wv (bijective, XCD-chunked); 4 units of
//   a block share n -> bf16 x-tile (~9KB) L1-hot for waves 1-3.
// Per-wave body: lane owns i=lane+64k, k=0..4 (k=4 only lane<32); v[5][8]
//   v2f; xt_bf[pixel][a][16] (4MB) + wt_bf[j][k][lane][16] (320KB) staged;
//   unnormalized softmax (SE rides butterfly), split-first butterfly,
//   xor1/2 DPP, xor4/8/16 ds_swizzle, p via v_readlane.
// FINAL LEDGER (10 rounds on the ~39µs main kernel):
//   real: XCD chunking (R16, -1.4µs), 4-wave blocks (R20, -0.6µs).
//   neutral: issue cuts (R14/R15), DPP/swizzle xlane (R14), occupancy
//     3->4 (R15, R22 clean).
//   negative: f32-direct x (R21, +3.0 clean — xt staging pays for itself),
//     LDS x-share (R12, +3.4).
//   fatal: serial multi-unit waves (R18/R19 — allocator parks v[5][8] in
//     scratch across unroll(1) loops; 165+µs). TRIPWIRE: VGPR_Count<100
//     or WRITE>>1MB = spill.
// PLATEAU: main ~39µs is per-wave serial latency (load -> transform ->
//   3x routing chains; ~18k cy/wave vs ~3k issue), insensitive to
//   residency and issue count; cross-wave decomposition proven negative.
//   Budget: ~41µs harness d_ws-poison fill (268MB, unconditional,
//   82% HBM peak, untouchable) + ~2.3µs stage + ~39µs main.

#define OH 15
#define OW 15
#define EPS_ 1e-8f

#define XT_ELEMS (2 * 32 * 32 * 512)        // 2,097,152 bf16 (4 MB)
#define WT_ELEMS (32 * 5 * 64 * 16)         // 163,840 bf16 (320 KB)

typedef float v2f __attribute__((ext_vector_type(2)));

__device__ __forceinline__ v2f pfma(float a, v2f b, v2f c) {
    return __builtin_elementwise_fma((v2f){a, a}, b, c);
}
__device__ __forceinline__ float b_lo(unsigned int u) {
    union { unsigned int i; float f; } c; c.i = u << 16; return c.f;
}
__device__ __forceinline__ float b_hi(unsigned int u) {
    union { unsigned int i; float f; } c; c.i = u & 0xFFFF0000u; return c.f;
}
__device__ __forceinline__ unsigned short f2bf(float f) {
    union { float f; unsigned int i; } c; c.f = f;
    return (unsigned short)((c.i + 0x7FFFu + ((c.i >> 16) & 1u)) >> 16); // RNE
}

// ---- cross-lane helpers (all wave-local: lane = tid&63) ----
// DPP quad_perm[1,0,3,2] = xor1 ; quad_perm[2,3,0,1] = xor2
__device__ __forceinline__ float dppx1(float x) {
    return __builtin_bit_cast(float, __builtin_amdgcn_update_dpp(
        0, __builtin_bit_cast(int, x), 0xB1, 0xF, 0xF, true));
}
__device__ __forceinline__ float dppx2(float x) {
    return __builtin_bit_cast(float, __builtin_amdgcn_update_dpp(
        0, __builtin_bit_cast(int, x), 0x4E, 0xF, 0xF, true));
}
// ds_swizzle BitMode: offset = (xor<<10)|(or<<5)|and, and=0x1F
template <int OFF>
__device__ __forceinline__ float swzx(float x) {
    return __builtin_bit_cast(float, __builtin_amdgcn_ds_swizzle(
        __builtin_bit_cast(int, x), OFF));
}
__device__ __forceinline__ float rdlane(float x, int q) {
    return __builtin_bit_cast(float, __builtin_amdgcn_readlane(
        __builtin_bit_cast(int, x), q));
}

// merged staging: [0, XT_ELEMS) casts x; [XT_ELEMS, +WT_ELEMS) permutes w
__global__ __launch_bounds__(256) void stage_kernel(
    const float* __restrict__ x, const float* __restrict__ w,
    unsigned short* __restrict__ xt, unsigned short* __restrict__ wt)
{
    const int tid = blockIdx.x * 256 + threadIdx.x;
    if (tid < XT_ELEMS) {
        xt[tid] = f2bf(x[tid]);
    } else {
        const int t2 = tid - XT_ELEMS;      // over WT_ELEMS
        const int j  = t2 / 5120;
        const int r  = t2 - j * 5120;
        const int k  = r >> 10;
        const int L  = (r >> 4) & 63;
        const int e  = r & 15;
        const int i  = L + 64 * k;
        wt[t2] = (i < 288) ? f2bf(w[(size_t)i * 512 + j * 16 + e])
                           : (unsigned short)0;
    }
}

template <bool PERM>
__global__ __launch_bounds__(256, 3) void convcaps_kernel(
    const void* __restrict__ xp,   // PERM ? bf16 xt : f32 x
    const void* __restrict__ wp_,  // PERM ? bf16 wt : f32 w
    float* __restrict__ out)       // (450,512)
{
    // 4 independent waves/block; wave wv handles unit
    //   (blk&7)*1800 + (blk>>3)*4 + wv   (bijective over 14400)
    // All 4 units of a block share n (base%32 multiple of 4, <=28).
    const int blk  = blockIdx.x;              // 0..3599
    const int wv   = threadIdx.x >> 6;        // 0..3
    const int wid  = (blk & 7) * 1800 + (blk >> 3) * 4 + wv;
    const int n    = wid >> 5;                // patch 0..449
    const int j    = wid & 31;                // out capsule
    const int lane = threadIdx.x & 63;        // 0..63

    const int batch = n / (OH * OW);
    const int rem   = n - batch * OH * OW;
    const int oy    = rem / OW;
    const int ox    = rem - oy * OW;

    const bool has5 = (lane < 32);

    v2f v[5][8];                      // v[k][p*2+qq]
    // inactive 5th slot: logit = -inf so exp -> 0 (drops has5 selects later)
    float logit[5] = {0.f, 0.f, 0.f, 0.f, has5 ? 0.f : -1e30f};

    // ---- v[k] = X_i(4x4) * W_ij(4x4), i = lane + 64k ----
#pragma unroll
    for (int k = 0; k < 5; ++k) {
        if (k == 4 && !has5) {
#pragma unroll
            for (int m = 0; m < 8; ++m) v[4][m] = (v2f){0.f, 0.f};
        } else {
            const int i  = lane + 64 * k;
            const int a  = i & 31;
            const int kw = (i >> 5) % 3;
            const int kh = i / 96;
            const int h  = oy * 2 + kh;
            const int wc = ox * 2 + kw;
            const int pixel = (batch * 32 + h) * 32 + wc;

            v2f wr2[4][2];
            if (PERM) {
                // xt[pixel][a][16] bf16: 32B contiguous per lane
                const uint4* xb = reinterpret_cast<const uint4*>(
                    (const unsigned short*)xp + ((size_t)pixel * 512 + a * 16));
                uint4 u0 = xb[0], u1 = xb[1];
                // wt[j][k][lane][16] bf16: 32B contiguous per lane
                const uint4* wb = reinterpret_cast<const uint4*>(
                    (const unsigned short*)wp_ + (((size_t)j * 5 + k) * 64 + lane) * 16);
                uint4 q0 = wb[0], q1 = wb[1];
                wr2[0][0] = (v2f){b_lo(q0.x), b_hi(q0.x)};
                wr2[0][1] = (v2f){b_lo(q0.y), b_hi(q0.y)};
                wr2[1][0] = (v2f){b_lo(q0.z), b_hi(q0.z)};
                wr2[1][1] = (v2f){b_lo(q0.w), b_hi(q0.w)};
                wr2[2][0] = (v2f){b_lo(q1.x), b_hi(q1.x)};
                wr2[2][1] = (v2f){b_lo(q1.y), b_hi(q1.y)};
                wr2[3][0] = (v2f){b_lo(q1.z), b_hi(q1.z)};
                wr2[3][1] = (v2f){b_lo(q1.w), b_hi(q1.w)};
                // row-at-a-time unpack: only 4 x-floats live at once
                const unsigned int dwp[8] = {u0.x, u0.y, u0.z, u0.w,
                                             u1.x, u1.y, u1.z, u1.w};
#pragma unroll
                for (int p = 0; p < 4; ++p) {
                    const unsigned int da = dwp[2*p], db = dwp[2*p+1];
                    const float x0 = b_lo(da), x1 = b_hi(da);
                    const float x2 = b_lo(db), x3 = b_hi(db);
#pragma unroll
                    for (int qq = 0; qq < 2; ++qq) {
                        v2f acc = (v2f){0.f, 0.f};
                        acc = pfma(x0, wr2[0][qq], acc);
                        acc = pfma(x1, wr2[1][qq], acc);
                        acc = pfma(x2, wr2[2][qq], acc);
                        acc = pfma(x3, wr2[3][qq], acc);
                        v[k][p*2+qq] = acc;
                    }
                }
            } else {
                const float4* xv = reinterpret_cast<const float4*>(
                    (const float*)xp + ((size_t)pixel * 512 + a * 16));
                const float4* wq = reinterpret_cast<const float4*>(
                    (const float*)wp_ + ((size_t)i * 32 + j) * 16);
                float4 w0 = wq[0], w1 = wq[1], w2 = wq[2], w3 = wq[3];
                wr2[0][0]=(v2f){w0.x,w0.y}; wr2[0][1]=(v2f){w0.z,w0.w};
                wr2[1][0]=(v2f){w1.x,w1.y}; wr2[1][1]=(v2f){w1.z,w1.w};
                wr2[2][0]=(v2f){w2.x,w2.y}; wr2[2][1]=(v2f){w2.z,w2.w};
                wr2[3][0]=(v2f){w3.x,w3.y}; wr2[3][1]=(v2f){w3.z,w3.w};
#pragma unroll
                for (int p = 0; p < 4; ++p) {
                    float4 xr4 = xv[p];
#pragma unroll
                    for (int qq = 0; qq < 2; ++qq) {
                        v2f acc = (v2f){0.f, 0.f};
                        acc = pfma(xr4.x, wr2[0][qq], acc);
                        acc = pfma(xr4.y, wr2[1][qq], acc);
                        acc = pfma(xr4.z, wr2[2][qq], acc);
                        acc = pfma(xr4.w, wr2[3][qq], acc);
                        v[k][p*2+qq] = acc;
                    }
                }
            }
        }
    }

#pragma unroll
    for (int it = 0; it < 3; ++it) {
        v2f c2[8];
        float se_loc;
        if (it == 0) {
#pragma unroll
            for (int m = 0; m < 8; ++m)
                c2[m] = v[0][m] + v[1][m] + v[2][m] + v[3][m] + v[4][m];
            se_loc = 0.f;  // normalizer is 288 (softmax of zeros)
        } else {
            const float e0 = __expf(logit[0]), e1 = __expf(logit[1]);
            const float e2 = __expf(logit[2]), e3 = __expf(logit[3]);
            const float e4 = __expf(logit[4]);   // 0 for lanes >= 32
#pragma unroll
            for (int m = 0; m < 8; ++m)
                c2[m] = pfma(e0, v[0][m],
                        pfma(e1, v[1][m],
                        pfma(e2, v[2][m],
                        pfma(e3, v[3][m],
                        pfma(e4, v[4][m], (v2f){0.f, 0.f})))));
            se_loc = e0 + e1 + e2 + e3 + e4;
        }

        float c[16];
#pragma unroll
        for (int m = 0; m < 8; ++m) { c[2*m] = c2[m].x; c[2*m+1] = c2[m].y; }

        // ---- split-first butterfly: comp bit b -> lane bit b ----
        float seR = se_loc;
        float s8[8];
        {
            const bool b = lane & 1;
#pragma unroll
            for (int m = 0; m < 8; ++m) {
                float send = b ? c[2*m]   : c[2*m+1];
                float keep = b ? c[2*m+1] : c[2*m];
                s8[m] = keep + dppx1(send);
            }
            if (it > 0) seR += dppx1(seR);
        }
        float s4[4];
        {
            const bool b = (lane >> 1) & 1;
#pragma unroll
            for (int m = 0; m < 4; ++m) {
                float send = b ? s8[2*m]   : s8[2*m+1];
                float keep = b ? s8[2*m+1] : s8[2*m];
                s4[m] = keep + dppx2(send);
            }
            if (it > 0) seR += dppx2(seR);
        }
        float s2v[2];
        {
            const bool b = (lane >> 2) & 1;
#pragma unroll
            for (int m = 0; m < 2; ++m) {
                float send = b ? s4[2*m]   : s4[2*m+1];
                float keep = b ? s4[2*m+1] : s4[2*m];
                s2v[m] = keep + swzx<0x101F>(send);
            }
            if (it > 0) seR += swzx<0x101F>(seR);
        }
        float s1;
        {
            const bool b = (lane >> 3) & 1;
            float send = b ? s2v[0] : s2v[1];
            float keep = b ? s2v[1] : s2v[0];
            s1 = keep + swzx<0x201F>(send);
            if (it > 0) seR += swzx<0x201F>(seR);
        }
        s1 += swzx<0x401F>(s1);    if (it > 0) seR += swzx<0x401F>(seR);
        s1 += __shfl_xor(s1, 32);  if (it > 0) seR += __shfl_xor(seR, 32);
        // s1 = sum_i (e_i or 1) * v_i[comp], comp = lane&15 ; seR = SE

        const float s = (it == 0) ? s1 * (1.0f / 288.0f)
                                  : s1 * __builtin_amdgcn_rcpf(seR);

        // ---- squash ----
        float t2 = s * s;
        t2 += dppx1(t2);
        t2 += dppx2(t2);
        t2 += swzx<0x101F>(t2);
        t2 += swzx<0x201F>(t2);
        const float n2 = t2;
        const float scale = n2 * __builtin_amdgcn_rcpf(1.0f + n2)
                               * __builtin_amdgcn_rsqf(n2 + EPS_);
        const float pval = s * scale;   // comp (lane&15) of p

        if (it < 2) {
            // p[q] identical at lanes q,q+16,q+32,q+48 -> readlane(q);
            // dot in packed v_pk_fma (acc.x even, acc.y odd chain).
            v2f pq2[8];
#pragma unroll
            for (int m = 0; m < 8; ++m)
                pq2[m] = (v2f){rdlane(pval, 2*m), rdlane(pval, 2*m+1)};
#pragma unroll
            for (int k = 0; k < 5; ++k) {
                v2f acc = (v2f){0.f, 0.f};
#pragma unroll
                for (int m = 0; m < 8; ++m)
                    acc = __builtin_elementwise_fma(v[k][m], pq2[m], acc);
                logit[k] += acc.x + acc.y;
            }
        } else {
            if (lane < 16)
                out[(size_t)n * 512 + j * 16 + lane] = pval;
        }
    }
}

extern "C" void kernel_launch(void* const* d_in, const int* in_sizes, int n_in,
                              void* d_out, int out_size, void* d_ws, size_t ws_size,
                              hipStream_t stream) {
    const float* x = (const float*)d_in[0];
    const float* w = (const float*)d_in[1];
    float* out = (float*)d_out;
    const int nblocks = 3600;   // 4 independent waves per block

    const size_t need = (size_t)(XT_ELEMS + WT_ELEMS) * sizeof(unsigned short);
    if (d_ws != nullptr && ws_size >= need) {
        unsigned short* xt = (unsigned short*)d_ws;
        unsigned short* wt = xt + XT_ELEMS;
        stage_kernel<<<(XT_ELEMS + WT_ELEMS) / 256, 256, 0, stream>>>(x, w, xt, wt);
        convcaps_kernel<true><<<nblocks, 256, 0, stream>>>(xt, wt, out);
    } else {
        convcaps_kernel<false><<<nblocks, 256, 0, stream>>>(x, w, out);
    }
}